// Round 5
// baseline (679.320 us; speedup 1.0000x reference)
//
#include <hip/hip_runtime.h>
#include <hip/hip_cooperative_groups.h>
#include <math.h>

namespace cg = cooperative_groups;

#define H 128
typedef unsigned int u32;
typedef unsigned long long u64;
typedef __attribute__((ext_vector_type(8))) short short8;
typedef __attribute__((ext_vector_type(4))) float floatx4;

#define XS_STRIDE 136   // bf16 elems per padded row (128 + 8) -> 272B
#define CS_STRIDE 40    // counts row stride (80B) -> conflict-free b128 reads

#define SCAN_B 64
#define SCAN_T 256

__device__ __forceinline__ float sigmoid_f(float x) {
    return 1.0f / (1.0f + __expf(-x));
}
__device__ __forceinline__ float tanh_f(float x) {
    float t = __expf(-2.0f * fabsf(x));
    float r = (1.0f - t) / (1.0f + t);
    return copysignf(r, x);
}
// f32 -> bf16 bits, round-to-nearest-even (finite inputs)
__device__ __forceinline__ unsigned short f2bf(float x) {
    u32 u = __float_as_uint(x);
    return (unsigned short)((u + 0x7fffu + ((u >> 16) & 1u)) >> 16);
}
__device__ __forceinline__ float bf2f(unsigned short s) {
    return __uint_as_float(((u32)s) << 16);
}
__device__ __forceinline__ float bf_lo32(u32 u) { return __uint_as_float(u << 16); }
__device__ __forceinline__ float bf_hi32(u32 u) { return __uint_as_float(u & 0xffff0000u); }

// ---------------------------------------------------------------------------
// Shared phase bodies (used by both the cooperative mega-kernel and the
// multi-launch fallback path).
// ---------------------------------------------------------------------------

// h (f32) -> h_b (bf16), 8 elems per item.
__device__ __forceinline__ void conv8_item(
    int idx, const float* __restrict__ h, unsigned short* __restrict__ h_b)
{
    const float4* p = (const float4*)(h + (size_t)idx * 8);
    float4 a = p[0], bb = p[1];
    short8 v;
    v[0] = (short)f2bf(a.x);  v[1] = (short)f2bf(a.y);
    v[2] = (short)f2bf(a.z);  v[3] = (short)f2bf(a.w);
    v[4] = (short)f2bf(bb.x); v[5] = (short)f2bf(bb.y);
    v[6] = (short)f2bf(bb.z); v[7] = (short)f2bf(bb.w);
    *(short8*)(h_b + (size_t)idx * 8) = v;
}

// Weight prep item (0..67583): W_c fold, embW', Whh swizzle.
// Swizzle (B-frag, 16x16x32): frag[((gtile*4+kc)*64 + l)*8 + i] =
//   W[(gtile*16 + (l&15))][kc*32 + (l>>4)*8 + i]
__device__ __forceinline__ void prep_item(
    int idx,
    const float* __restrict__ Wih, const float* __restrict__ Whh,
    const float* __restrict__ Wm,  const float* __restrict__ emb,
    const float* __restrict__ bm,
    unsigned short* __restrict__ Wcs, unsigned short* __restrict__ Whhs,
    unsigned short* __restrict__ embWs)
{
    if (idx < 49152) {
        // ---- W_c[g][k] = sum_c Wih[g][c] * Wm[c][k], f32 acc -> bf16 swizzled
        int g = idx >> 7;          // 0..383
        int k = idx & 127;
        float acc = 0.f;
#pragma unroll 4
        for (int c = 0; c < H; ++c)
            acc += Wih[(size_t)g * H + c] * Wm[(size_t)c * H + k];
        int gate = g >> 7;
        int wi = g & 127;
        int j = wi >> 4, m = wi & 15;
        int kc = k >> 5, q = (k >> 3) & 3, i = k & 7;
        int l = q * 16 + m;
        Wcs[(size_t)(((gate * 8 + j) * 4 + kc) * 64 + l) * 8 + i] = f2bf(acc);
    } else if (idx < 61440) {
        // ---- embW'[t][g] = sum_j (emb[t][j]+bm[j])*Wih[g][j], K=32 frag
        int s = idx - 49152;       // 0..12287
        int i = s & 7;
        int l = (s >> 3) & 63;
        int jb = s >> 9;           // gate*8 + j
        int gate = jb >> 3, jj = jb & 7;
        int q = l >> 4, m = l & 15;
        int t = q * 8 + i;         // edge type (K index)
        unsigned short v = 0;
        if (t < 9) {
            int g = gate * 128 + jj * 16 + m;
            float acc = 0.f;
#pragma unroll 4
            for (int jx = 0; jx < H; ++jx)
                acc += (emb[(size_t)t * H + jx] + bm[jx]) * Wih[(size_t)g * H + jx];
            v = f2bf(acc);
        }
        embWs[s] = v;
    } else if (idx < 67584) {
        // ---- Whh convert + swizzle
        int t2 = idx - 61440;      // 0..6143
        int l  = t2 & 63;
        int kc = (t2 >> 6) & 3;
        int jr = t2 >> 8;
        int m = l & 15, q = l >> 4;
        size_t srco = (size_t)(jr * 16 + m) * H + kc * 32 + q * 8;
        const float4* s0 = (const float4*)(Whh + srco);
        float4 a = s0[0], bb = s0[1];
        short8 v;
        v[0] = (short)f2bf(a.x);  v[1] = (short)f2bf(a.y);
        v[2] = (short)f2bf(a.z);  v[3] = (short)f2bf(a.w);
        v[4] = (short)f2bf(bb.x); v[5] = (short)f2bf(bb.y);
        v[6] = (short)f2bf(bb.z); v[7] = (short)f2bf(bb.w);
        *(short8*)(Whhs + (size_t)t2 * 8) = v;
    }
}

// Gather for one node n (one full wave): S[n] = sum h_b[src], cnt[n] packed.
__device__ __forceinline__ void gather_node(
    int n, int lane,
    const unsigned short* __restrict__ h_b,
    const int* __restrict__ off, const int* __restrict__ packed,
    unsigned short* __restrict__ S_b, u64* __restrict__ cnt)
{
    int b = off[n], e = off[n + 1];
    float ax = 0.f, ay = 0.f;
    u64 c = 0;
    int i = b;
    for (; i + 8 <= e; i += 8) {
        int u0 = packed[i + 0];
        int u1 = packed[i + 1];
        int u2 = packed[i + 2];
        int u3 = packed[i + 3];
        int u4 = packed[i + 4];
        int u5 = packed[i + 5];
        int u6 = packed[i + 6];
        int u7 = packed[i + 7];
        u32 x0 = *((const u32*)(h_b + (size_t)(u0 & 0xffffff) * H) + lane);
        u32 x1 = *((const u32*)(h_b + (size_t)(u1 & 0xffffff) * H) + lane);
        u32 x2 = *((const u32*)(h_b + (size_t)(u2 & 0xffffff) * H) + lane);
        u32 x3 = *((const u32*)(h_b + (size_t)(u3 & 0xffffff) * H) + lane);
        u32 x4 = *((const u32*)(h_b + (size_t)(u4 & 0xffffff) * H) + lane);
        u32 x5 = *((const u32*)(h_b + (size_t)(u5 & 0xffffff) * H) + lane);
        u32 x6 = *((const u32*)(h_b + (size_t)(u6 & 0xffffff) * H) + lane);
        u32 x7 = *((const u32*)(h_b + (size_t)(u7 & 0xffffff) * H) + lane);
        c += (1ull << (7 * (u0 >> 24))) + (1ull << (7 * (u1 >> 24)))
           + (1ull << (7 * (u2 >> 24))) + (1ull << (7 * (u3 >> 24)))
           + (1ull << (7 * (u4 >> 24))) + (1ull << (7 * (u5 >> 24)))
           + (1ull << (7 * (u6 >> 24))) + (1ull << (7 * (u7 >> 24)));
        ax += bf_lo32(x0) + bf_lo32(x1) + bf_lo32(x2) + bf_lo32(x3)
            + bf_lo32(x4) + bf_lo32(x5) + bf_lo32(x6) + bf_lo32(x7);
        ay += bf_hi32(x0) + bf_hi32(x1) + bf_hi32(x2) + bf_hi32(x3)
            + bf_hi32(x4) + bf_hi32(x5) + bf_hi32(x6) + bf_hi32(x7);
    }
    for (; i + 4 <= e; i += 4) {
        int u0 = packed[i + 0];
        int u1 = packed[i + 1];
        int u2 = packed[i + 2];
        int u3 = packed[i + 3];
        u32 x0 = *((const u32*)(h_b + (size_t)(u0 & 0xffffff) * H) + lane);
        u32 x1 = *((const u32*)(h_b + (size_t)(u1 & 0xffffff) * H) + lane);
        u32 x2 = *((const u32*)(h_b + (size_t)(u2 & 0xffffff) * H) + lane);
        u32 x3 = *((const u32*)(h_b + (size_t)(u3 & 0xffffff) * H) + lane);
        c += (1ull << (7 * (u0 >> 24))) + (1ull << (7 * (u1 >> 24)))
           + (1ull << (7 * (u2 >> 24))) + (1ull << (7 * (u3 >> 24)));
        ax += bf_lo32(x0) + bf_lo32(x1) + bf_lo32(x2) + bf_lo32(x3);
        ay += bf_hi32(x0) + bf_hi32(x1) + bf_hi32(x2) + bf_hi32(x3);
    }
    for (; i < e; ++i) {
        int u = packed[i];
        u32 x = *((const u32*)(h_b + (size_t)(u & 0xffffff) * H) + lane);
        c += 1ull << (7 * (u >> 24));
        ax += bf_lo32(x);
        ay += bf_hi32(x);
    }
    u32 o = (u32)f2bf(ax) | ((u32)f2bf(ay) << 16);
    *((u32*)(S_b + (size_t)n * H) + lane) = o;
    if (lane == 0) cnt[n] = c;
}

// GRU for one (64-node tile, jhalf) work unit. Enters with arbitrary LDS
// content (leading barrier), leaves LDS free for the next unit.
__device__ __forceinline__ void gru_unit(
    int node0, int jhalf, int tid,
    unsigned short* xs, unsigned short* hsb, unsigned short* cs,
    const unsigned short* __restrict__ S_b, const unsigned short* __restrict__ h_b,
    const unsigned short* __restrict__ Wcs, const unsigned short* __restrict__ Whhs,
    const unsigned short* __restrict__ embWs,
    const float* __restrict__ bih, const float* __restrict__ bhh,
    const u64* __restrict__ cnt, int num_nodes,
    float* __restrict__ out, int N)
{
    int lane = tid & 63;
    int wv = tid >> 6;
    int j = jhalf * 4 + wv;      // this wave's j-tile (0..7)

    __syncthreads();   // previous unit (if any) done with LDS

    // prefetch emb fragments (independent of staging)
    short8 er = *(const short8*)(embWs + (size_t)((0 * 8 + j) * 64 + lane) * 8);
    short8 ez = *(const short8*)(embWs + (size_t)((1 * 8 + j) * 64 + lane) * 8);
    short8 en = *(const short8*)(embWs + (size_t)((2 * 8 + j) * 64 + lane) * 8);

    for (int c = tid; c < 1024; c += 256) {
        int r = c >> 4;
        int k8 = (c & 15) << 3;
        int n = node0 + r;
        int nc = n < N ? n : N - 1;
        *(short8*)(&xs[r * XS_STRIDE + k8]) =
            *(const short8*)(S_b + (size_t)nc * H + k8);
        *(short8*)(&hsb[r * XS_STRIDE + k8]) =
            *(const short8*)(h_b + (size_t)nc * H + k8);
    }
    {
        // counts tile: row r, type-group tg covers t = tg*8 .. tg*8+7 (t<9 live)
        int r = tid >> 2, tg = tid & 3;
        int n = node0 + r;
        u64 cv = cnt[n < N ? n : N - 1];
        short8 v = {0, 0, 0, 0, 0, 0, 0, 0};
        if (tg == 0) {
#pragma unroll
            for (int i = 0; i < 8; ++i)
                v[i] = (short)f2bf((float)((u32)(cv >> (7 * i)) & 127u));
        } else if (tg == 1) {
            v[0] = (short)f2bf((float)((u32)(cv >> 56) & 127u));
        }
        *(short8*)(&cs[r * CS_STRIDE + tg * 8]) = v;
    }
    __syncthreads();

    int am = lane & 15;
    int aq = lane >> 4;

    floatx4 zero = {0.f, 0.f, 0.f, 0.f};
    floatx4 aR[4], aZ[4], aIn[4], aHn[4];
#pragma unroll
    for (int rt = 0; rt < 4; ++rt) {
        short8 acn = *(const short8*)(&cs[(rt * 16 + am) * CS_STRIDE + aq * 8]);
        aR[rt]  = __builtin_amdgcn_mfma_f32_16x16x32_bf16(acn, er, zero, 0, 0, 0);
        aZ[rt]  = __builtin_amdgcn_mfma_f32_16x16x32_bf16(acn, ez, zero, 0, 0, 0);
        aIn[rt] = __builtin_amdgcn_mfma_f32_16x16x32_bf16(acn, en, zero, 0, 0, 0);
        aHn[rt] = zero;
    }
#pragma unroll
    for (int kc = 0; kc < 4; ++kc) {
        size_t c_r = (size_t)(((0 * 8 + j) * 4 + kc) * 64 + lane) * 8;
        size_t c_z = (size_t)(((1 * 8 + j) * 4 + kc) * 64 + lane) * 8;
        size_t c_n = (size_t)(((2 * 8 + j) * 4 + kc) * 64 + lane) * 8;
        short8 bir = *(const short8*)(Wcs + c_r);
        short8 bhr = *(const short8*)(Whhs + c_r);
        short8 biz = *(const short8*)(Wcs + c_z);
        short8 bhz = *(const short8*)(Whhs + c_z);
        short8 bin = *(const short8*)(Wcs + c_n);
        short8 bhn = *(const short8*)(Whhs + c_n);
#pragma unroll
        for (int rt = 0; rt < 4; ++rt) {
            int arow = rt * 16 + am;
            short8 axv = *(const short8*)(&xs[arow * XS_STRIDE + kc * 32 + aq * 8]);
            short8 ahv = *(const short8*)(&hsb[arow * XS_STRIDE + kc * 32 + aq * 8]);
            aR[rt]  = __builtin_amdgcn_mfma_f32_16x16x32_bf16(axv, bir, aR[rt], 0, 0, 0);
            aR[rt]  = __builtin_amdgcn_mfma_f32_16x16x32_bf16(ahv, bhr, aR[rt], 0, 0, 0);
            aZ[rt]  = __builtin_amdgcn_mfma_f32_16x16x32_bf16(axv, biz, aZ[rt], 0, 0, 0);
            aZ[rt]  = __builtin_amdgcn_mfma_f32_16x16x32_bf16(ahv, bhz, aZ[rt], 0, 0, 0);
            aIn[rt] = __builtin_amdgcn_mfma_f32_16x16x32_bf16(axv, bin, aIn[rt], 0, 0, 0);
            aHn[rt] = __builtin_amdgcn_mfma_f32_16x16x32_bf16(ahv, bhn, aHn[rt], 0, 0, 0);
        }
    }
    int c = j * 16 + am;
    float b_r = bih[c]       + bhh[c];
    float b_z = bih[128 + c] + bhh[128 + c];
    float b_in = bih[256 + c], b_hn = bhh[256 + c];
#pragma unroll
    for (int rt = 0; rt < 4; ++rt) {
#pragma unroll
        for (int q = 0; q < 4; ++q) {
            int m = rt * 16 + aq * 4 + q;
            int node = node0 + m;
            if (node < N) {
                float r  = sigmoid_f(aR[rt][q] + b_r);
                float z  = sigmoid_f(aZ[rt][q] + b_z);
                float nv = tanh_f((aIn[rt][q] + b_in) + r * (aHn[rt][q] + b_hn));
                float hv = bf2f(hsb[m * XS_STRIDE + c]);
                float o  = (1.0f - z) * nv + z * hv;
                out[(size_t)node * H + c] = (node < num_nodes) ? o : 0.0f;
            }
        }
    }
}

// ---------------------------------------------------------------------------
// Cooperative mega-kernel: the ENTIRE pipeline in one launch.
// Phases separated by grid.sync(); all work grid-stride so any grid size
// works. LDS (gru staging buffers) doubles as scan scratch.
// ---------------------------------------------------------------------------
__global__ __launch_bounds__(256, 2) void mega_kernel(
    const float* __restrict__ h, unsigned short* __restrict__ h_b, int total8,
    const int* __restrict__ eidx, const int* __restrict__ etype, int E,
    int* __restrict__ deg, int* __restrict__ off, int* __restrict__ pos,
    int* __restrict__ packed, int* __restrict__ mbsum, int* __restrict__ mbpre,
    const float* __restrict__ Wih, const float* __restrict__ Whh,
    const float* __restrict__ Wm,  const float* __restrict__ emb,
    const float* __restrict__ bm,
    unsigned short* __restrict__ Wcs, unsigned short* __restrict__ Whhs,
    unsigned short* __restrict__ embWs,
    unsigned short* __restrict__ S_b, u64* __restrict__ cnt,
    const float* __restrict__ bih, const float* __restrict__ bhh,
    const int* __restrict__ numn, float* __restrict__ out, int N)
{
    __shared__ unsigned short xs[64 * XS_STRIDE];    // 17408 B (also scan scratch)
    __shared__ unsigned short hsb[64 * XS_STRIDE];   // 17408 B (also P2b scratch)
    __shared__ unsigned short cs[64 * CS_STRIDE];    //  5120 B

    cg::grid_group grid = cg::this_grid();
    int tid = threadIdx.x;
    int nb  = gridDim.x;
    int T   = nb * 256;
    int gid = blockIdx.x * 256 + tid;

    // ---------------- P0: h convert + deg zero + weight prep ----------------
    for (int idx = gid; idx < total8; idx += T) conv8_item(idx, h, h_b);
    for (int idx = gid; idx < N; idx += T) deg[idx] = 0;
    for (int idx = gid; idx < 67584; idx += T)
        prep_item(idx, Wih, Whh, Wm, emb, bm, Wcs, Whhs, embWs);
    __threadfence();
    grid.sync();

    // ---------------- P1: degree histogram ----------------
    for (int e = gid; e < E; e += T) atomicAdd(&deg[eidx[E + e]], 1);
    __threadfence();
    grid.sync();

    // ---------------- P2a: per-thread chunk sums + block scan ----------------
    int ipt = (N + T - 1) / T;
    int* sscan = (int*)xs;            // per-block thread-prefix (persists!)
    {
        int s = gid * ipt;
        int en = s + ipt < N ? s + ipt : N;
        int sum = 0;
        for (int i = s; i < en; ++i) sum += deg[i];
        sscan[tid] = sum;
        __syncthreads();
        for (int d = 1; d < 256; d <<= 1) {
            int v = (tid >= d) ? sscan[tid - d] : 0;
            __syncthreads();
            sscan[tid] += v;
            __syncthreads();
        }
        if (tid == 255) mbsum[blockIdx.x] = sscan[255];
    }
    __threadfence();
    grid.sync();

    // ---------------- P2b: block 0 scans the <=512 block sums ----------------
    if (blockIdx.x == 0) {
        int* ps = (int*)hsb;          // pair-sum scan scratch
        int b0 = (2 * tid     < nb) ? mbsum[2 * tid]     : 0;
        int b1 = (2 * tid + 1 < nb) ? mbsum[2 * tid + 1] : 0;
        ps[tid] = b0 + b1;
        __syncthreads();
        for (int d = 1; d < 256; d <<= 1) {
            int v = (tid >= d) ? ps[tid - d] : 0;
            __syncthreads();
            ps[tid] += v;
            __syncthreads();
        }
        int excl_pair = tid ? ps[tid - 1] : 0;
        if (2 * tid     < nb) mbpre[2 * tid]     = excl_pair;
        if (2 * tid + 1 < nb) mbpre[2 * tid + 1] = excl_pair + b0;
        if (tid == 255) off[N] = ps[255];
    }
    __threadfence();
    grid.sync();

    // ---------------- P2c: write off/pos (thread prefixes preserved in LDS) --
    {
        int base = mbpre[blockIdx.x] + (tid ? sscan[tid - 1] : 0);
        int s = gid * ipt;
        int en = s + ipt < N ? s + ipt : N;
        for (int i = s; i < en; ++i) {
            off[i] = base;
            pos[i] = base;
            base += deg[i];
        }
    }
    __threadfence();
    grid.sync();

    // ---------------- P3: fill (scatter edges into CSR slots) ----------------
    for (int e = gid; e < E; e += T) {
        int src = eidx[e];
        int dst = eidx[E + e];
        int t = etype[e];
        t = t < 0 ? 0 : (t > 8 ? 8 : t);
        int p = atomicAdd(&pos[dst], 1);
        packed[p] = src | (t << 24);
    }
    __threadfence();
    grid.sync();

    // ---------------- P4: gather (wave per node) ----------------
    {
        int lane = tid & 63, wv = tid >> 6;
        for (int n = blockIdx.x * 4 + wv; n < N; n += nb * 4)
            gather_node(n, lane, h_b, off, packed, S_b, cnt);
    }
    __threadfence();
    grid.sync();

    // ---------------- P5: GRU (64-node tile x jhalf work units) ----------------
    {
        int num_nodes = numn[0];
        int nunits = ((N + 63) / 64) * 2;
        for (int u = blockIdx.x; u < nunits; u += nb)
            gru_unit((u >> 1) * 64, u & 1, tid, xs, hsb, cs,
                     S_b, h_b, Wcs, Whhs, embWs, bih, bhh, cnt,
                     num_nodes, out, N);
    }
}

// ---------------------------------------------------------------------------
// Fallback multi-launch path (r4 pipeline), used if cooperative launch is
// unavailable. Shares the same device phase bodies.
// ---------------------------------------------------------------------------
__global__ __launch_bounds__(256) void fused_pre_kernel(
    const float* __restrict__ h, unsigned short* __restrict__ h_b, int total8,
    int* __restrict__ deg, int N,
    const float* __restrict__ Wih, const float* __restrict__ Whh,
    const float* __restrict__ Wm,  const float* __restrict__ emb,
    const float* __restrict__ bm,
    unsigned short* __restrict__ Wcs, unsigned short* __restrict__ Whhs,
    unsigned short* __restrict__ embWs, int HB, int DB)
{
    int b = blockIdx.x;
    if (b < HB) {
        int idx = b * 256 + threadIdx.x;
        if (idx < total8) conv8_item(idx, h, h_b);
        return;
    }
    if (b < HB + DB) {
        int idx = (b - HB) * 256 + threadIdx.x;
        if (idx < N) deg[idx] = 0;
        return;
    }
    int idx = (b - HB - DB) * 256 + threadIdx.x;
    prep_item(idx, Wih, Whh, Wm, emb, bm, Wcs, Whhs, embWs);
}

__global__ __launch_bounds__(256) void hist_kernel(
    const int* __restrict__ eidx, int* __restrict__ deg, int E)
{
    int e = blockIdx.x * 256 + threadIdx.x;
    if (e < E) atomicAdd(&deg[eidx[E + e]], 1);
}

__global__ __launch_bounds__(SCAN_T) void scan_part_kernel(
    const int* __restrict__ deg, int* __restrict__ tsum,
    int* __restrict__ bsum, int N, int ipt)
{
    __shared__ int red[SCAN_T];
    int t = threadIdx.x;
    int g = blockIdx.x * SCAN_T + t;
    int s = g * ipt;
    int e = s + ipt < N ? s + ipt : N;
    int sum = 0;
    for (int i = s; i < e; ++i) sum += deg[i];
    tsum[g] = sum;
    red[t] = sum;
    __syncthreads();
    for (int d = SCAN_T / 2; d > 0; d >>= 1) {
        if (t < d) red[t] += red[t + d];
        __syncthreads();
    }
    if (t == 0) bsum[blockIdx.x] = red[0];
}

__global__ __launch_bounds__(SCAN_T) void scan_final_kernel(
    const int* __restrict__ deg, const int* __restrict__ tsum,
    const int* __restrict__ bsum, int* __restrict__ off,
    int* __restrict__ pos, int N, int ipt)
{
    __shared__ int part[SCAN_T];
    __shared__ int bpre[SCAN_B + 1];
    int t = threadIdx.x;
    if (t == 0) {
        int acc = 0;
        for (int b2 = 0; b2 < SCAN_B; ++b2) { bpre[b2] = acc; acc += bsum[b2]; }
        bpre[SCAN_B] = acc;
        if (blockIdx.x == 0) off[N] = acc;
    }
    int g = blockIdx.x * SCAN_T + t;
    part[t] = tsum[g];
    __syncthreads();
    for (int d = 1; d < SCAN_T; d <<= 1) {
        int v = (t >= d) ? part[t - d] : 0;
        __syncthreads();
        part[t] += v;
        __syncthreads();
    }
    int base = bpre[blockIdx.x] + ((t == 0) ? 0 : part[t - 1]);
    int s = g * ipt;
    int e = s + ipt < N ? s + ipt : N;
    for (int i = s; i < e; ++i) {
        off[i] = base;
        pos[i] = base;
        base += deg[i];
    }
}

__global__ __launch_bounds__(256) void fill_kernel(
    const int* __restrict__ eidx, const int* __restrict__ etype,
    int* __restrict__ pos, int* __restrict__ packed, int E)
{
    int e = blockIdx.x * 256 + threadIdx.x;
    if (e >= E) return;
    int src = eidx[e];
    int dst = eidx[E + e];
    int t = etype[e];
    t = t < 0 ? 0 : (t > 8 ? 8 : t);
    int p = atomicAdd(&pos[dst], 1);
    packed[p] = src | (t << 24);
}

__global__ __launch_bounds__(256) void gather_kernel(
    const unsigned short* __restrict__ h_b,
    const int* __restrict__ off, const int* __restrict__ packed,
    unsigned short* __restrict__ S_b, u64* __restrict__ cnt, int N)
{
    int n = blockIdx.x * 4 + (threadIdx.x >> 6);
    if (n >= N) return;
    gather_node(n, threadIdx.x & 63, h_b, off, packed, S_b, cnt);
}

__global__ __launch_bounds__(256, 4) void gru_mfma_kernel(
    const unsigned short* __restrict__ S_b, const unsigned short* __restrict__ h_b,
    const unsigned short* __restrict__ Wcs, const unsigned short* __restrict__ Whhs,
    const unsigned short* __restrict__ embWs,
    const float* __restrict__ bih, const float* __restrict__ bhh,
    const u64* __restrict__ cnt,
    const int* __restrict__ numn, float* __restrict__ out, int N)
{
    __shared__ unsigned short xs[64 * XS_STRIDE];
    __shared__ unsigned short hsb[64 * XS_STRIDE];
    __shared__ unsigned short cs[64 * CS_STRIDE];
    int bx = blockIdx.x;
    gru_unit((bx >> 1) * 64, bx & 1, threadIdx.x, xs, hsb, cs,
             S_b, h_b, Wcs, Whhs, embWs, bih, bhh, cnt, numn[0], out, N);
}

extern "C" void kernel_launch(void* const* d_in, const int* in_sizes, int n_in,
                              void* d_out, int out_size, void* d_ws, size_t ws_size,
                              hipStream_t stream) {
    const float* h    = (const float*)d_in[0];
    const int*  eidx  = (const int*)d_in[1];
    const int*  etype = (const int*)d_in[2];
    const int*  numn  = (const int*)d_in[3];
    const float* Wm   = (const float*)d_in[4];
    const float* bm   = (const float*)d_in[5];
    const float* emb  = (const float*)d_in[6];
    const float* Wih  = (const float*)d_in[7];
    const float* Whh  = (const float*)d_in[8];
    const float* bih  = (const float*)d_in[9];
    const float* bhh  = (const float*)d_in[10];

    int N = in_sizes[0] / H;
    int E = in_sizes[2];

    // ws layout:
    unsigned short* S_b   = (unsigned short*)d_ws;               // N*H bf16
    unsigned short* h_b   = S_b + (size_t)N * H;                 // N*H bf16
    unsigned short* Wcs   = h_b + (size_t)N * H;                 // 3*H*H (swizzled)
    unsigned short* Whhs  = Wcs + 3 * H * H;                     // 3*H*H (swizzled)
    unsigned short* embWs = Whhs + 3 * H * H;                    // 3*8*64*8 = 12288
    u64* cnt    = (u64*)(embWs + 12288);                         // N (8B-aligned)
    int* deg    = (int*)(cnt + N);                               // N
    int* pos    = deg + N;                                       // N
    int* off    = pos + N;                                       // N+1
    int* packed = off + (N + 1);                                 // E
    int* tsum   = packed + E;                                    // SCAN_B*SCAN_T
    int* bsum   = tsum + SCAN_B * SCAN_T;                        // SCAN_B
    int* mbsum  = tsum;                                          // 512 (mega)
    int* mbpre  = tsum + 1024;                                   // 513 (mega)
    float* outp = (float*)d_out;

    int total8 = N * H / 8;

    // One-time cooperative capability / grid-size probe.
    static int coop_grid = -2;
    if (coop_grid == -2) {
        int nbpc = 0;
        hipError_t e1 = hipOccupancyMaxActiveBlocksPerMultiprocessor(
            &nbpc, mega_kernel, 256, 0);
        int ncu = 0;
        hipDeviceProp_t prop;
        if (hipGetDeviceProperties(&prop, 0) == hipSuccess)
            ncu = prop.multiProcessorCount;
        if (e1 == hipSuccess && nbpc > 0 && ncu > 0) {
            long g = (long)nbpc * (long)ncu;
            coop_grid = (int)(g > 512 ? 512 : g);
        } else {
            coop_grid = -1;
        }
    }

    bool done = false;
    if (coop_grid > 0) {
        void* kargs[] = {
            (void*)&h, (void*)&h_b, (void*)&total8,
            (void*)&eidx, (void*)&etype, (void*)&E,
            (void*)&deg, (void*)&off, (void*)&pos, (void*)&packed,
            (void*)&mbsum, (void*)&mbpre,
            (void*)&Wih, (void*)&Whh, (void*)&Wm, (void*)&emb, (void*)&bm,
            (void*)&Wcs, (void*)&Whhs, (void*)&embWs,
            (void*)&S_b, (void*)&cnt,
            (void*)&bih, (void*)&bhh, (void*)&numn,
            (void*)&outp, (void*)&N
        };
        hipError_t err = hipLaunchCooperativeKernel(
            (void*)mega_kernel, dim3((unsigned)coop_grid), dim3(256),
            kargs, 0u, stream);
        if (err == hipSuccess) {
            done = true;
        } else {
            coop_grid = -1;   // don't retry; fall back permanently
        }
    }

    if (!done) {
        int HB = (total8 + 255) / 256;
        int DB = (N + 255) / 256;
        int PB = 264;
        fused_pre_kernel<<<HB + DB + PB, 256, 0, stream>>>(
            h, h_b, total8, deg, N, Wih, Whh, Wm, emb, bm, Wcs, Whhs, embWs, HB, DB);

        hist_kernel<<<(E + 255) / 256, 256, 0, stream>>>(eidx, deg, E);

        int ipt = (N + SCAN_B * SCAN_T - 1) / (SCAN_B * SCAN_T);
        scan_part_kernel<<<SCAN_B, SCAN_T, 0, stream>>>(deg, tsum, bsum, N, ipt);
        scan_final_kernel<<<SCAN_B, SCAN_T, 0, stream>>>(deg, tsum, bsum, off, pos, N, ipt);

        fill_kernel<<<(E + 255) / 256, 256, 0, stream>>>(eidx, etype, pos, packed, E);

        gather_kernel<<<(N + 3) / 4, 256, 0, stream>>>(h_b, off, packed, S_b, cnt, N);

        int nblk = ((N + 63) / 64) * 2;
        gru_mfma_kernel<<<nblk, 256, 0, stream>>>(S_b, h_b, Wcs, Whhs, embWs,
                                                  bih, bhh, cnt, numn, outp, N);
    }
}

// Round 6
// 222.302 us; speedup vs baseline: 3.0558x; 3.0558x over previous
//
#include <hip/hip_runtime.h>
#include <math.h>

#define H 128
typedef unsigned int u32;
typedef unsigned long long u64;
typedef __attribute__((ext_vector_type(8))) short short8;
typedef __attribute__((ext_vector_type(4))) float floatx4;

#define XS_STRIDE 136   // bf16 elems per padded row (128 + 8) -> 272B
#define CS_STRIDE 40    // counts row stride (80B) -> conflict-free b128 reads

__device__ __forceinline__ float sigmoid_f(float x) {
    return 1.0f / (1.0f + __expf(-x));
}
__device__ __forceinline__ float tanh_f(float x) {
    float t = __expf(-2.0f * fabsf(x));
    float r = (1.0f - t) / (1.0f + t);
    return copysignf(r, x);
}
// f32 -> bf16 bits, round-to-nearest-even (finite inputs)
__device__ __forceinline__ unsigned short f2bf(float x) {
    u32 u = __float_as_uint(x);
    return (unsigned short)((u + 0x7fffu + ((u >> 16) & 1u)) >> 16);
}
__device__ __forceinline__ float bf2f(unsigned short s) {
    return __uint_as_float(((u32)s) << 16);
}
__device__ __forceinline__ float bf_lo32(u32 u) { return __uint_as_float(u << 16); }
__device__ __forceinline__ float bf_hi32(u32 u) { return __uint_as_float(u & 0xffff0000u); }

// ---------------------------------------------------------------------------
// Fused pre-pass: [blocks 0..HB)   h (f32) -> h_b (bf16)
//                 [HB..HB+DB)      head[] = -1 (linked-list heads)
//                 [HB+DB..)        weight prep (W_c fold, embW', Whh swizzle)
// Swizzle (B-frag, 16x16x32): frag[((gtile*4+kc)*64 + l)*8 + i] =
//   W[(gtile*16 + (l&15))][kc*32 + (l>>4)*8 + i]
// ---------------------------------------------------------------------------
__global__ __launch_bounds__(256) void fused_pre_kernel(
    const float* __restrict__ h, unsigned short* __restrict__ h_b, int total8,
    int* __restrict__ head, int N,
    const float* __restrict__ Wih, const float* __restrict__ Whh,
    const float* __restrict__ Wm,  const float* __restrict__ emb,
    const float* __restrict__ bm,
    unsigned short* __restrict__ Wcs, unsigned short* __restrict__ Whhs,
    unsigned short* __restrict__ embWs, int HB, int DB)
{
    int b = blockIdx.x;
    if (b < HB) {
        int idx = b * 256 + threadIdx.x;
        if (idx >= total8) return;
        const float4* p = (const float4*)(h + (size_t)idx * 8);
        float4 a = p[0], bb = p[1];
        short8 v;
        v[0] = (short)f2bf(a.x);  v[1] = (short)f2bf(a.y);
        v[2] = (short)f2bf(a.z);  v[3] = (short)f2bf(a.w);
        v[4] = (short)f2bf(bb.x); v[5] = (short)f2bf(bb.y);
        v[6] = (short)f2bf(bb.z); v[7] = (short)f2bf(bb.w);
        *(short8*)(h_b + (size_t)idx * 8) = v;
        return;
    }
    if (b < HB + DB) {
        int idx = (b - HB) * 256 + threadIdx.x;
        if (idx < N) head[idx] = -1;
        return;
    }
    int idx = (b - HB - DB) * 256 + threadIdx.x;
    if (idx < 49152) {
        // ---- W_c[g][k] = sum_c Wih[g][c] * Wm[c][k], f32 acc -> bf16 swizzled
        int g = idx >> 7;          // 0..383
        int k = idx & 127;
        float acc = 0.f;
#pragma unroll 4
        for (int c = 0; c < H; ++c)
            acc += Wih[(size_t)g * H + c] * Wm[(size_t)c * H + k];
        int gate = g >> 7;
        int wi = g & 127;
        int j = wi >> 4, m = wi & 15;
        int kc = k >> 5, q = (k >> 3) & 3, i = k & 7;
        int l = q * 16 + m;
        Wcs[(size_t)(((gate * 8 + j) * 4 + kc) * 64 + l) * 8 + i] = f2bf(acc);
    } else if (idx < 61440) {
        // ---- embW'[t][g] = sum_j (emb[t][j]+bm[j])*Wih[g][j], K=32 frag
        int s = idx - 49152;       // 0..12287
        int i = s & 7;
        int l = (s >> 3) & 63;
        int jb = s >> 9;           // gate*8 + j
        int gate = jb >> 3, jj = jb & 7;
        int q = l >> 4, m = l & 15;
        int t = q * 8 + i;         // edge type (K index)
        unsigned short v = 0;
        if (t < 9) {
            int g = gate * 128 + jj * 16 + m;
            float acc = 0.f;
#pragma unroll 4
            for (int jx = 0; jx < H; ++jx)
                acc += (emb[(size_t)t * H + jx] + bm[jx]) * Wih[(size_t)g * H + jx];
            v = f2bf(acc);
        }
        embWs[s] = v;
    } else if (idx < 67584) {
        // ---- Whh convert + swizzle
        int t2 = idx - 61440;      // 0..6143
        int l  = t2 & 63;
        int kc = (t2 >> 6) & 3;
        int jr = t2 >> 8;
        int m = l & 15, q = l >> 4;
        size_t srco = (size_t)(jr * 16 + m) * H + kc * 32 + q * 8;
        const float4* s0 = (const float4*)(Whh + srco);
        float4 a = s0[0], bb = s0[1];
        short8 v;
        v[0] = (short)f2bf(a.x);  v[1] = (short)f2bf(a.y);
        v[2] = (short)f2bf(a.z);  v[3] = (short)f2bf(a.w);
        v[4] = (short)f2bf(bb.x); v[5] = (short)f2bf(bb.y);
        v[6] = (short)f2bf(bb.z); v[7] = (short)f2bf(bb.w);
        *(short8*)(Whhs + (size_t)t2 * 8) = v;
    }
}

// ---------------------------------------------------------------------------
// Linked-list build (replaces hist + scan + scan + fill):
//   packed[e] = src | type<<24 ; next[e] = atomicExch(&head[dst], e)
// ---------------------------------------------------------------------------
__global__ __launch_bounds__(256) void fill_ll_kernel(
    const int* __restrict__ eidx, const int* __restrict__ etype,
    int* __restrict__ head, int* __restrict__ nexte,
    int* __restrict__ packed, int E)
{
    int e = blockIdx.x * 256 + threadIdx.x;
    if (e >= E) return;
    int src = eidx[e];
    int dst = eidx[E + e];
    int t = etype[e];
    t = t < 0 ? 0 : (t > 8 ? 8 : t);
    packed[e] = src | (t << 24);
    int old = atomicExch(&head[dst], e);
    nexte[e] = old;
}

// ---------------------------------------------------------------------------
// Gather via chain-chase: S[n] = sum_{e in chain(n)} h_b[src_e], cnt[n]
// packed 7-bit type counters. One wave = 4 nodes, chains chased CONCURRENTLY
// (4x MLP on the ~600-cycle dependent next[] loads). All chain state is
// wave-uniform -> branches are exec-uniform.
// ---------------------------------------------------------------------------
__global__ __launch_bounds__(256) void gather_ll_kernel(
    const unsigned short* __restrict__ h_b,
    const int* __restrict__ head, const int* __restrict__ nexte,
    const int* __restrict__ packed,
    unsigned short* __restrict__ S_b, u64* __restrict__ cnt, int N)
{
    int w = blockIdx.x * 4 + (threadIdx.x >> 6);
    int lane = threadIdx.x & 63;
    int n0 = w * 4;
    if (n0 >= N) return;

    int e0 = head[n0];
    int e1 = (n0 + 1 < N) ? head[n0 + 1] : -1;
    int e2 = (n0 + 2 < N) ? head[n0 + 2] : -1;
    int e3 = (n0 + 3 < N) ? head[n0 + 3] : -1;

    float ax0 = 0.f, ay0 = 0.f, ax1 = 0.f, ay1 = 0.f;
    float ax2 = 0.f, ay2 = 0.f, ax3 = 0.f, ay3 = 0.f;
    u64 c0 = 0, c1 = 0, c2 = 0, c3 = 0;

    while ((e0 >= 0) || (e1 >= 0) || (e2 >= 0) || (e3 >= 0)) {
        int nx0 = -1, nx1 = -1, nx2 = -1, nx3 = -1;
        int u0 = 0, u1 = 0, u2 = 0, u3 = 0;
        if (e0 >= 0) { nx0 = nexte[e0]; u0 = packed[e0]; }
        if (e1 >= 0) { nx1 = nexte[e1]; u1 = packed[e1]; }
        if (e2 >= 0) { nx2 = nexte[e2]; u2 = packed[e2]; }
        if (e3 >= 0) { nx3 = nexte[e3]; u3 = packed[e3]; }
        if (e0 >= 0) {
            u32 x = *((const u32*)(h_b + (size_t)(u0 & 0xffffff) * H) + lane);
            c0 += 1ull << (7 * (u0 >> 24));
            ax0 += bf_lo32(x); ay0 += bf_hi32(x);
        }
        if (e1 >= 0) {
            u32 x = *((const u32*)(h_b + (size_t)(u1 & 0xffffff) * H) + lane);
            c1 += 1ull << (7 * (u1 >> 24));
            ax1 += bf_lo32(x); ay1 += bf_hi32(x);
        }
        if (e2 >= 0) {
            u32 x = *((const u32*)(h_b + (size_t)(u2 & 0xffffff) * H) + lane);
            c2 += 1ull << (7 * (u2 >> 24));
            ax2 += bf_lo32(x); ay2 += bf_hi32(x);
        }
        if (e3 >= 0) {
            u32 x = *((const u32*)(h_b + (size_t)(u3 & 0xffffff) * H) + lane);
            c3 += 1ull << (7 * (u3 >> 24));
            ax3 += bf_lo32(x); ay3 += bf_hi32(x);
        }
        e0 = nx0; e1 = nx1; e2 = nx2; e3 = nx3;
    }

    {
        u32 o = (u32)f2bf(ax0) | ((u32)f2bf(ay0) << 16);
        *((u32*)(S_b + (size_t)n0 * H) + lane) = o;
        if (lane == 0) cnt[n0] = c0;
    }
    if (n0 + 1 < N) {
        u32 o = (u32)f2bf(ax1) | ((u32)f2bf(ay1) << 16);
        *((u32*)(S_b + (size_t)(n0 + 1) * H) + lane) = o;
        if (lane == 0) cnt[n0 + 1] = c1;
    }
    if (n0 + 2 < N) {
        u32 o = (u32)f2bf(ax2) | ((u32)f2bf(ay2) << 16);
        *((u32*)(S_b + (size_t)(n0 + 2) * H) + lane) = o;
        if (lane == 0) cnt[n0 + 2] = c2;
    }
    if (n0 + 3 < N) {
        u32 o = (u32)f2bf(ax3) | ((u32)f2bf(ay3) << 16);
        *((u32*)(S_b + (size_t)(n0 + 3) * H) + lane) = o;
        if (lane == 0) cnt[n0 + 3] = c3;
    }
}

// ---------------------------------------------------------------------------
// Fused GRU (MFMA). Block = (64-node tile) x (jhalf of 4 j-tiles); 4 waves,
// each wave owns ONE j-tile and loops 4 row-tiles (accs register-resident,
// weights loaded once per kc). Grid = 2x node-tiles (~1564 blocks) for
// latency hiding; LDS 39.9KB -> 4 resident blocks/CU. (r4-proven structure.)
//   aR = counts@embW_r + S@Wc_r^T + h@Whh_r^T    (gate-shared accumulators)
//   aZ = counts@embW_z + S@Wc_z^T + h@Whh_z^T
//   aIn = counts@embW_n + S@Wc_n^T ; aHn = h@Whh_n^T
// ---------------------------------------------------------------------------
__global__ __launch_bounds__(256, 4) void gru_mfma_kernel(
    const unsigned short* __restrict__ S_b, const unsigned short* __restrict__ h_b,
    const unsigned short* __restrict__ Wcs, const unsigned short* __restrict__ Whhs,
    const unsigned short* __restrict__ embWs,
    const float* __restrict__ bih, const float* __restrict__ bhh,
    const u64* __restrict__ cnt,
    const int* __restrict__ numn, float* __restrict__ out, int N)
{
    __shared__ unsigned short xs[64 * XS_STRIDE];    // 17408 B
    __shared__ unsigned short hsb[64 * XS_STRIDE];   // 17408 B
    __shared__ unsigned short cs[64 * CS_STRIDE];    //  5120 B

    int tid = threadIdx.x;
    int bx = blockIdx.x;
    int node0 = (bx >> 1) * 64;
    int jhalf = bx & 1;

    int lane = tid & 63;
    int wv = tid >> 6;
    int j = jhalf * 4 + wv;      // this wave's j-tile (0..7)

    // prefetch emb fragments (independent of staging; completes under barrier)
    short8 er = *(const short8*)(embWs + (size_t)((0 * 8 + j) * 64 + lane) * 8);
    short8 ez = *(const short8*)(embWs + (size_t)((1 * 8 + j) * 64 + lane) * 8);
    short8 en = *(const short8*)(embWs + (size_t)((2 * 8 + j) * 64 + lane) * 8);

    for (int c = tid; c < 1024; c += 256) {
        int r = c >> 4;
        int k8 = (c & 15) << 3;
        int n = node0 + r;
        int nc = n < N ? n : N - 1;
        *(short8*)(&xs[r * XS_STRIDE + k8]) =
            *(const short8*)(S_b + (size_t)nc * H + k8);
        *(short8*)(&hsb[r * XS_STRIDE + k8]) =
            *(const short8*)(h_b + (size_t)nc * H + k8);
    }
    {
        // counts tile: row r, type-group tg covers t = tg*8 .. tg*8+7 (t<9 live)
        int r = tid >> 2, tg = tid & 3;
        int n = node0 + r;
        u64 cv = cnt[n < N ? n : N - 1];
        short8 v = {0, 0, 0, 0, 0, 0, 0, 0};
        if (tg == 0) {
#pragma unroll
            for (int i = 0; i < 8; ++i)
                v[i] = (short)f2bf((float)((u32)(cv >> (7 * i)) & 127u));
        } else if (tg == 1) {
            v[0] = (short)f2bf((float)((u32)(cv >> 56) & 127u));
        }
        *(short8*)(&cs[r * CS_STRIDE + tg * 8]) = v;
    }
    __syncthreads();

    int am = lane & 15;
    int aq = lane >> 4;

    int num_nodes = numn[0];
    floatx4 zero = {0.f, 0.f, 0.f, 0.f};

    floatx4 aR[4], aZ[4], aIn[4], aHn[4];
#pragma unroll
    for (int rt = 0; rt < 4; ++rt) {
        short8 acn = *(const short8*)(&cs[(rt * 16 + am) * CS_STRIDE + aq * 8]);
        aR[rt]  = __builtin_amdgcn_mfma_f32_16x16x32_bf16(acn, er, zero, 0, 0, 0);
        aZ[rt]  = __builtin_amdgcn_mfma_f32_16x16x32_bf16(acn, ez, zero, 0, 0, 0);
        aIn[rt] = __builtin_amdgcn_mfma_f32_16x16x32_bf16(acn, en, zero, 0, 0, 0);
        aHn[rt] = zero;
    }
#pragma unroll
    for (int kc = 0; kc < 4; ++kc) {
        size_t c_r = (size_t)(((0 * 8 + j) * 4 + kc) * 64 + lane) * 8;
        size_t c_z = (size_t)(((1 * 8 + j) * 4 + kc) * 64 + lane) * 8;
        size_t c_n = (size_t)(((2 * 8 + j) * 4 + kc) * 64 + lane) * 8;
        short8 bir = *(const short8*)(Wcs + c_r);
        short8 bhr = *(const short8*)(Whhs + c_r);
        short8 biz = *(const short8*)(Wcs + c_z);
        short8 bhz = *(const short8*)(Whhs + c_z);
        short8 bin = *(const short8*)(Wcs + c_n);
        short8 bhn = *(const short8*)(Whhs + c_n);
#pragma unroll
        for (int rt = 0; rt < 4; ++rt) {
            int arow = rt * 16 + am;
            short8 axv = *(const short8*)(&xs[arow * XS_STRIDE + kc * 32 + aq * 8]);
            short8 ahv = *(const short8*)(&hsb[arow * XS_STRIDE + kc * 32 + aq * 8]);
            aR[rt]  = __builtin_amdgcn_mfma_f32_16x16x32_bf16(axv, bir, aR[rt], 0, 0, 0);
            aR[rt]  = __builtin_amdgcn_mfma_f32_16x16x32_bf16(ahv, bhr, aR[rt], 0, 0, 0);
            aZ[rt]  = __builtin_amdgcn_mfma_f32_16x16x32_bf16(axv, biz, aZ[rt], 0, 0, 0);
            aZ[rt]  = __builtin_amdgcn_mfma_f32_16x16x32_bf16(ahv, bhz, aZ[rt], 0, 0, 0);
            aIn[rt] = __builtin_amdgcn_mfma_f32_16x16x32_bf16(axv, bin, aIn[rt], 0, 0, 0);
            aHn[rt] = __builtin_amdgcn_mfma_f32_16x16x32_bf16(ahv, bhn, aHn[rt], 0, 0, 0);
        }
    }
    int c = j * 16 + am;
    float b_r = bih[c]       + bhh[c];
    float b_z = bih[128 + c] + bhh[128 + c];
    float b_in = bih[256 + c], b_hn = bhh[256 + c];
#pragma unroll
    for (int rt = 0; rt < 4; ++rt) {
#pragma unroll
        for (int q = 0; q < 4; ++q) {
            int m = rt * 16 + aq * 4 + q;
            int node = node0 + m;
            if (node < N) {
                float r  = sigmoid_f(aR[rt][q] + b_r);
                float z  = sigmoid_f(aZ[rt][q] + b_z);
                float nv = tanh_f((aIn[rt][q] + b_in) + r * (aHn[rt][q] + b_hn));
                float hv = bf2f(hsb[m * XS_STRIDE + c]);
                float o  = (1.0f - z) * nv + z * hv;
                out[(size_t)node * H + c] = (node < num_nodes) ? o : 0.0f;
            }
        }
    }
}

extern "C" void kernel_launch(void* const* d_in, const int* in_sizes, int n_in,
                              void* d_out, int out_size, void* d_ws, size_t ws_size,
                              hipStream_t stream) {
    const float* h    = (const float*)d_in[0];
    const int*  eidx  = (const int*)d_in[1];
    const int*  etype = (const int*)d_in[2];
    const int*  numn  = (const int*)d_in[3];
    const float* Wm   = (const float*)d_in[4];
    const float* bm   = (const float*)d_in[5];
    const float* emb  = (const float*)d_in[6];
    const float* Wih  = (const float*)d_in[7];
    const float* Whh  = (const float*)d_in[8];
    const float* bih  = (const float*)d_in[9];
    const float* bhh  = (const float*)d_in[10];

    int N = in_sizes[0] / H;
    int E = in_sizes[2];

    // ws layout:
    unsigned short* S_b   = (unsigned short*)d_ws;               // N*H bf16
    unsigned short* h_b   = S_b + (size_t)N * H;                 // N*H bf16
    unsigned short* Wcs   = h_b + (size_t)N * H;                 // 3*H*H (swizzled)
    unsigned short* Whhs  = Wcs + 3 * H * H;                     // 3*H*H (swizzled)
    unsigned short* embWs = Whhs + 3 * H * H;                    // 3*8*64*8 = 12288
    u64* cnt    = (u64*)(embWs + 12288);                         // N (8B-aligned)
    int* head   = (int*)(cnt + N);                               // N
    int* packed = head + N;                                      // E
    int* nexte  = packed + E;                                    // E

    int total8 = N * H / 8;
    int HB = (total8 + 255) / 256;
    int DB = (N + 255) / 256;
    int PB = 264;
    fused_pre_kernel<<<HB + DB + PB, 256, 0, stream>>>(
        h, h_b, total8, head, N, Wih, Whh, Wm, emb, bm, Wcs, Whhs, embWs, HB, DB);

    fill_ll_kernel<<<(E + 255) / 256, 256, 0, stream>>>(
        eidx, etype, head, nexte, packed, E);

    gather_ll_kernel<<<(N + 15) / 16, 256, 0, stream>>>(
        h_b, head, nexte, packed, S_b, cnt, N);

    int nblk = ((N + 63) / 64) * 2;
    gru_mfma_kernel<<<nblk, 256, 0, stream>>>(S_b, h_b, Wcs, Whhs, embWs,
                                              bih, bhh, cnt, numn, (float*)d_out, N);
}

// Round 7
// 219.767 us; speedup vs baseline: 3.0911x; 1.0115x over previous
//
#include <hip/hip_runtime.h>
#include <math.h>

#define H 128
typedef unsigned int u32;
typedef unsigned long long u64;
typedef __attribute__((ext_vector_type(8))) short short8;
typedef __attribute__((ext_vector_type(4))) float floatx4;

#define XS_STRIDE 136   // bf16 elems per padded row (128 + 8) -> 272B
#define CS_STRIDE 40    // counts row stride (80B) -> conflict-free b128 reads

__device__ __forceinline__ float sigmoid_f(float x) {
    return 1.0f / (1.0f + __expf(-x));
}
__device__ __forceinline__ float tanh_f(float x) {
    float t = __expf(-2.0f * fabsf(x));
    float r = (1.0f - t) / (1.0f + t);
    return copysignf(r, x);
}
// f32 -> bf16 bits, round-to-nearest-even (finite inputs)
__device__ __forceinline__ unsigned short f2bf(float x) {
    u32 u = __float_as_uint(x);
    return (unsigned short)((u + 0x7fffu + ((u >> 16) & 1u)) >> 16);
}
__device__ __forceinline__ float bf2f(unsigned short s) {
    return __uint_as_float(((u32)s) << 16);
}
__device__ __forceinline__ float bf_lo32(u32 u) { return __uint_as_float(u << 16); }
__device__ __forceinline__ float bf_hi32(u32 u) { return __uint_as_float(u & 0xffff0000u); }

// ---------------------------------------------------------------------------
// Fused pre-pass: [blocks 0..HB)   h (f32) -> h_b (bf16)
//                 [HB..HB+DB)      head[] = -1 (4 sub-list heads per node)
//                 [HB+DB..)        weight prep (W_c fold, embW', Whh swizzle)
// Swizzle (B-frag, 16x16x32): frag[((gtile*4+kc)*64 + l)*8 + i] =
//   W[(gtile*16 + (l&15))][kc*32 + (l>>4)*8 + i]
// ---------------------------------------------------------------------------
__global__ __launch_bounds__(256) void fused_pre_kernel(
    const float* __restrict__ h, unsigned short* __restrict__ h_b, int total8,
    int* __restrict__ head, int N4,
    const float* __restrict__ Wih, const float* __restrict__ Whh,
    const float* __restrict__ Wm,  const float* __restrict__ emb,
    const float* __restrict__ bm,
    unsigned short* __restrict__ Wcs, unsigned short* __restrict__ Whhs,
    unsigned short* __restrict__ embWs, int HB, int DB)
{
    int b = blockIdx.x;
    if (b < HB) {
        int idx = b * 256 + threadIdx.x;
        if (idx >= total8) return;
        const float4* p = (const float4*)(h + (size_t)idx * 8);
        float4 a = p[0], bb = p[1];
        short8 v;
        v[0] = (short)f2bf(a.x);  v[1] = (short)f2bf(a.y);
        v[2] = (short)f2bf(a.z);  v[3] = (short)f2bf(a.w);
        v[4] = (short)f2bf(bb.x); v[5] = (short)f2bf(bb.y);
        v[6] = (short)f2bf(bb.z); v[7] = (short)f2bf(bb.w);
        *(short8*)(h_b + (size_t)idx * 8) = v;
        return;
    }
    if (b < HB + DB) {
        int idx = (b - HB) * 256 + threadIdx.x;
        if (idx < N4) head[idx] = -1;
        return;
    }
    int idx = (b - HB - DB) * 256 + threadIdx.x;
    if (idx < 49152) {
        // ---- W_c[g][k] = sum_c Wih[g][c] * Wm[c][k], f32 acc -> bf16 swizzled
        int g = idx >> 7;          // 0..383
        int k = idx & 127;
        float acc = 0.f;
#pragma unroll 4
        for (int c = 0; c < H; ++c)
            acc += Wih[(size_t)g * H + c] * Wm[(size_t)c * H + k];
        int gate = g >> 7;
        int wi = g & 127;
        int j = wi >> 4, m = wi & 15;
        int kc = k >> 5, q = (k >> 3) & 3, i = k & 7;
        int l = q * 16 + m;
        Wcs[(size_t)(((gate * 8 + j) * 4 + kc) * 64 + l) * 8 + i] = f2bf(acc);
    } else if (idx < 61440) {
        // ---- embW'[t][g] = sum_j (emb[t][j]+bm[j])*Wih[g][j], K=32 frag
        int s = idx - 49152;       // 0..12287
        int i = s & 7;
        int l = (s >> 3) & 63;
        int jb = s >> 9;           // gate*8 + j
        int gate = jb >> 3, jj = jb & 7;
        int q = l >> 4, m = l & 15;
        int t = q * 8 + i;         // edge type (K index)
        unsigned short v = 0;
        if (t < 9) {
            int g = gate * 128 + jj * 16 + m;
            float acc = 0.f;
#pragma unroll 4
            for (int jx = 0; jx < H; ++jx)
                acc += (emb[(size_t)t * H + jx] + bm[jx]) * Wih[(size_t)g * H + jx];
            v = f2bf(acc);
        }
        embWs[s] = v;
    } else if (idx < 67584) {
        // ---- Whh convert + swizzle
        int t2 = idx - 61440;      // 0..6143
        int l  = t2 & 63;
        int kc = (t2 >> 6) & 3;
        int jr = t2 >> 8;
        int m = l & 15, q = l >> 4;
        size_t srco = (size_t)(jr * 16 + m) * H + kc * 32 + q * 8;
        const float4* s0 = (const float4*)(Whh + srco);
        float4 a = s0[0], bb = s0[1];
        short8 v;
        v[0] = (short)f2bf(a.x);  v[1] = (short)f2bf(a.y);
        v[2] = (short)f2bf(a.z);  v[3] = (short)f2bf(a.w);
        v[4] = (short)f2bf(bb.x); v[5] = (short)f2bf(bb.y);
        v[6] = (short)f2bf(bb.z); v[7] = (short)f2bf(bb.w);
        *(short8*)(Whhs + (size_t)t2 * 8) = v;
    }
}

// ---------------------------------------------------------------------------
// Linked-list build: 4 sub-lists per node (slot = e & 3) to shorten chains.
//   packed[e] = src | type<<24 ; next[e] = atomicExch(&head[dst*4+slot], e)
// ---------------------------------------------------------------------------
__global__ __launch_bounds__(256) void fill_ll_kernel(
    const int* __restrict__ eidx, const int* __restrict__ etype,
    int* __restrict__ head, int* __restrict__ nexte,
    int* __restrict__ packed, int E)
{
    int e = blockIdx.x * 256 + threadIdx.x;
    if (e >= E) return;
    int src = eidx[e];
    int dst = eidx[E + e];
    int t = etype[e];
    t = t < 0 ? 0 : (t > 8 ? 8 : t);
    packed[e] = src | (t << 24);
    int old = atomicExch(&head[dst * 4 + (e & 3)], e);
    nexte[e] = old;
}

// ---------------------------------------------------------------------------
// Gather via multi-chain chase: S[n] = sum_{e in chains(n)} h_b[src_e],
// cnt[n] packed 7-bit type counters. One wave = 2 nodes x 4 sub-chains = 8
// chains chased CONCURRENTLY (expected length E/N/4 = 3; dependent-round
// count ~ max-of-8 ~ 7 vs 18 for single-list). All chain state wave-uniform.
// ---------------------------------------------------------------------------
__global__ __launch_bounds__(256) void gather_ll_kernel(
    const unsigned short* __restrict__ h_b,
    const int* __restrict__ head, const int* __restrict__ nexte,
    const int* __restrict__ packed,
    unsigned short* __restrict__ S_b, u64* __restrict__ cnt, int N)
{
    int w = blockIdx.x * 4 + (threadIdx.x >> 6);
    int lane = threadIdx.x & 63;
    int n0 = w * 2;
    if (n0 >= N) return;
    bool has1 = (n0 + 1) < N;

    int e0 = head[n0 * 4 + 0];
    int e1 = head[n0 * 4 + 1];
    int e2 = head[n0 * 4 + 2];
    int e3 = head[n0 * 4 + 3];
    int e4 = has1 ? head[n0 * 4 + 4] : -1;
    int e5 = has1 ? head[n0 * 4 + 5] : -1;
    int e6 = has1 ? head[n0 * 4 + 6] : -1;
    int e7 = has1 ? head[n0 * 4 + 7] : -1;

    float ax0 = 0.f, ay0 = 0.f, ax1 = 0.f, ay1 = 0.f;
    u64 c0 = 0, c1 = 0;

    while ((e0 | e1 | e2 | e3 | e4 | e5 | e6 | e7) >= 0 ||
           e0 >= 0 || e1 >= 0 || e2 >= 0 || e3 >= 0 ||
           e4 >= 0 || e5 >= 0 || e6 >= 0 || e7 >= 0) {
        int nx0 = -1, nx1 = -1, nx2 = -1, nx3 = -1;
        int nx4 = -1, nx5 = -1, nx6 = -1, nx7 = -1;
        int u0 = 0, u1 = 0, u2 = 0, u3 = 0;
        int u4 = 0, u5 = 0, u6 = 0, u7 = 0;
        if (e0 >= 0) { nx0 = nexte[e0]; u0 = packed[e0]; }
        if (e1 >= 0) { nx1 = nexte[e1]; u1 = packed[e1]; }
        if (e2 >= 0) { nx2 = nexte[e2]; u2 = packed[e2]; }
        if (e3 >= 0) { nx3 = nexte[e3]; u3 = packed[e3]; }
        if (e4 >= 0) { nx4 = nexte[e4]; u4 = packed[e4]; }
        if (e5 >= 0) { nx5 = nexte[e5]; u5 = packed[e5]; }
        if (e6 >= 0) { nx6 = nexte[e6]; u6 = packed[e6]; }
        if (e7 >= 0) { nx7 = nexte[e7]; u7 = packed[e7]; }
        if (e0 >= 0) {
            u32 x = *((const u32*)(h_b + (size_t)(u0 & 0xffffff) * H) + lane);
            c0 += 1ull << (7 * (u0 >> 24));
            ax0 += bf_lo32(x); ay0 += bf_hi32(x);
        }
        if (e1 >= 0) {
            u32 x = *((const u32*)(h_b + (size_t)(u1 & 0xffffff) * H) + lane);
            c0 += 1ull << (7 * (u1 >> 24));
            ax0 += bf_lo32(x); ay0 += bf_hi32(x);
        }
        if (e2 >= 0) {
            u32 x = *((const u32*)(h_b + (size_t)(u2 & 0xffffff) * H) + lane);
            c0 += 1ull << (7 * (u2 >> 24));
            ax0 += bf_lo32(x); ay0 += bf_hi32(x);
        }
        if (e3 >= 0) {
            u32 x = *((const u32*)(h_b + (size_t)(u3 & 0xffffff) * H) + lane);
            c0 += 1ull << (7 * (u3 >> 24));
            ax0 += bf_lo32(x); ay0 += bf_hi32(x);
        }
        if (e4 >= 0) {
            u32 x = *((const u32*)(h_b + (size_t)(u4 & 0xffffff) * H) + lane);
            c1 += 1ull << (7 * (u4 >> 24));
            ax1 += bf_lo32(x); ay1 += bf_hi32(x);
        }
        if (e5 >= 0) {
            u32 x = *((const u32*)(h_b + (size_t)(u5 & 0xffffff) * H) + lane);
            c1 += 1ull << (7 * (u5 >> 24));
            ax1 += bf_lo32(x); ay1 += bf_hi32(x);
        }
        if (e6 >= 0) {
            u32 x = *((const u32*)(h_b + (size_t)(u6 & 0xffffff) * H) + lane);
            c1 += 1ull << (7 * (u6 >> 24));
            ax1 += bf_lo32(x); ay1 += bf_hi32(x);
        }
        if (e7 >= 0) {
            u32 x = *((const u32*)(h_b + (size_t)(u7 & 0xffffff) * H) + lane);
            c1 += 1ull << (7 * (u7 >> 24));
            ax1 += bf_lo32(x); ay1 += bf_hi32(x);
        }
        e0 = nx0; e1 = nx1; e2 = nx2; e3 = nx3;
        e4 = nx4; e5 = nx5; e6 = nx6; e7 = nx7;
    }

    {
        u32 o = (u32)f2bf(ax0) | ((u32)f2bf(ay0) << 16);
        *((u32*)(S_b + (size_t)n0 * H) + lane) = o;
        if (lane == 0) cnt[n0] = c0;
    }
    if (has1) {
        u32 o = (u32)f2bf(ax1) | ((u32)f2bf(ay1) << 16);
        *((u32*)(S_b + (size_t)(n0 + 1) * H) + lane) = o;
        if (lane == 0) cnt[n0 + 1] = c1;
    }
}

// ---------------------------------------------------------------------------
// Fused GRU (MFMA). Block = (64-node tile) x (jhalf of 4 j-tiles); 4 waves,
// each wave owns ONE j-tile and loops 4 row-tiles (accs register-resident,
// weights loaded once per kc). Grid = 2x node-tiles (~1564 blocks) for
// latency hiding; LDS 39.9KB -> 4 resident blocks/CU. (r4-proven structure.)
//   aR = counts@embW_r + S@Wc_r^T + h@Whh_r^T    (gate-shared accumulators)
//   aZ = counts@embW_z + S@Wc_z^T + h@Whh_z^T
//   aIn = counts@embW_n + S@Wc_n^T ; aHn = h@Whh_n^T
// ---------------------------------------------------------------------------
__global__ __launch_bounds__(256, 4) void gru_mfma_kernel(
    const unsigned short* __restrict__ S_b, const unsigned short* __restrict__ h_b,
    const unsigned short* __restrict__ Wcs, const unsigned short* __restrict__ Whhs,
    const unsigned short* __restrict__ embWs,
    const float* __restrict__ bih, const float* __restrict__ bhh,
    const u64* __restrict__ cnt,
    const int* __restrict__ numn, float* __restrict__ out, int N)
{
    __shared__ unsigned short xs[64 * XS_STRIDE];    // 17408 B
    __shared__ unsigned short hsb[64 * XS_STRIDE];   // 17408 B
    __shared__ unsigned short cs[64 * CS_STRIDE];    //  5120 B

    int tid = threadIdx.x;
    int bx = blockIdx.x;
    int node0 = (bx >> 1) * 64;
    int jhalf = bx & 1;

    int lane = tid & 63;
    int wv = tid >> 6;
    int j = jhalf * 4 + wv;      // this wave's j-tile (0..7)

    // prefetch emb fragments (independent of staging; completes under barrier)
    short8 er = *(const short8*)(embWs + (size_t)((0 * 8 + j) * 64 + lane) * 8);
    short8 ez = *(const short8*)(embWs + (size_t)((1 * 8 + j) * 64 + lane) * 8);
    short8 en = *(const short8*)(embWs + (size_t)((2 * 8 + j) * 64 + lane) * 8);

    for (int c = tid; c < 1024; c += 256) {
        int r = c >> 4;
        int k8 = (c & 15) << 3;
        int n = node0 + r;
        int nc = n < N ? n : N - 1;
        *(short8*)(&xs[r * XS_STRIDE + k8]) =
            *(const short8*)(S_b + (size_t)nc * H + k8);
        *(short8*)(&hsb[r * XS_STRIDE + k8]) =
            *(const short8*)(h_b + (size_t)nc * H + k8);
    }
    {
        // counts tile: row r, type-group tg covers t = tg*8 .. tg*8+7 (t<9 live)
        int r = tid >> 2, tg = tid & 3;
        int n = node0 + r;
        u64 cv = cnt[n < N ? n : N - 1];
        short8 v = {0, 0, 0, 0, 0, 0, 0, 0};
        if (tg == 0) {
#pragma unroll
            for (int i = 0; i < 8; ++i)
                v[i] = (short)f2bf((float)((u32)(cv >> (7 * i)) & 127u));
        } else if (tg == 1) {
            v[0] = (short)f2bf((float)((u32)(cv >> 56) & 127u));
        }
        *(short8*)(&cs[r * CS_STRIDE + tg * 8]) = v;
    }
    __syncthreads();

    int am = lane & 15;
    int aq = lane >> 4;

    int num_nodes = numn[0];
    floatx4 zero = {0.f, 0.f, 0.f, 0.f};

    floatx4 aR[4], aZ[4], aIn[4], aHn[4];
#pragma unroll
    for (int rt = 0; rt < 4; ++rt) {
        short8 acn = *(const short8*)(&cs[(rt * 16 + am) * CS_STRIDE + aq * 8]);
        aR[rt]  = __builtin_amdgcn_mfma_f32_16x16x32_bf16(acn, er, zero, 0, 0, 0);
        aZ[rt]  = __builtin_amdgcn_mfma_f32_16x16x32_bf16(acn, ez, zero, 0, 0, 0);
        aIn[rt] = __builtin_amdgcn_mfma_f32_16x16x32_bf16(acn, en, zero, 0, 0, 0);
        aHn[rt] = zero;
    }
#pragma unroll
    for (int kc = 0; kc < 4; ++kc) {
        size_t c_r = (size_t)(((0 * 8 + j) * 4 + kc) * 64 + lane) * 8;
        size_t c_z = (size_t)(((1 * 8 + j) * 4 + kc) * 64 + lane) * 8;
        size_t c_n = (size_t)(((2 * 8 + j) * 4 + kc) * 64 + lane) * 8;
        short8 bir = *(const short8*)(Wcs + c_r);
        short8 bhr = *(const short8*)(Whhs + c_r);
        short8 biz = *(const short8*)(Wcs + c_z);
        short8 bhz = *(const short8*)(Whhs + c_z);
        short8 bin = *(const short8*)(Wcs + c_n);
        short8 bhn = *(const short8*)(Whhs + c_n);
#pragma unroll
        for (int rt = 0; rt < 4; ++rt) {
            int arow = rt * 16 + am;
            short8 axv = *(const short8*)(&xs[arow * XS_STRIDE + kc * 32 + aq * 8]);
            short8 ahv = *(const short8*)(&hsb[arow * XS_STRIDE + kc * 32 + aq * 8]);
            aR[rt]  = __builtin_amdgcn_mfma_f32_16x16x32_bf16(axv, bir, aR[rt], 0, 0, 0);
            aR[rt]  = __builtin_amdgcn_mfma_f32_16x16x32_bf16(ahv, bhr, aR[rt], 0, 0, 0);
            aZ[rt]  = __builtin_amdgcn_mfma_f32_16x16x32_bf16(axv, biz, aZ[rt], 0, 0, 0);
            aZ[rt]  = __builtin_amdgcn_mfma_f32_16x16x32_bf16(ahv, bhz, aZ[rt], 0, 0, 0);
            aIn[rt] = __builtin_amdgcn_mfma_f32_16x16x32_bf16(axv, bin, aIn[rt], 0, 0, 0);
            aHn[rt] = __builtin_amdgcn_mfma_f32_16x16x32_bf16(ahv, bhn, aHn[rt], 0, 0, 0);
        }
    }
    int c = j * 16 + am;
    float b_r = bih[c]       + bhh[c];
    float b_z = bih[128 + c] + bhh[128 + c];
    float b_in = bih[256 + c], b_hn = bhh[256 + c];
#pragma unroll
    for (int rt = 0; rt < 4; ++rt) {
#pragma unroll
        for (int q = 0; q < 4; ++q) {
            int m = rt * 16 + aq * 4 + q;
            int node = node0 + m;
            if (node < N) {
                float r  = sigmoid_f(aR[rt][q] + b_r);
                float z  = sigmoid_f(aZ[rt][q] + b_z);
                float nv = tanh_f((aIn[rt][q] + b_in) + r * (aHn[rt][q] + b_hn));
                float hv = bf2f(hsb[m * XS_STRIDE + c]);
                float o  = (1.0f - z) * nv + z * hv;
                out[(size_t)node * H + c] = (node < num_nodes) ? o : 0.0f;
            }
        }
    }
}

extern "C" void kernel_launch(void* const* d_in, const int* in_sizes, int n_in,
                              void* d_out, int out_size, void* d_ws, size_t ws_size,
                              hipStream_t stream) {
    const float* h    = (const float*)d_in[0];
    const int*  eidx  = (const int*)d_in[1];
    const int*  etype = (const int*)d_in[2];
    const int*  numn  = (const int*)d_in[3];
    const float* Wm   = (const float*)d_in[4];
    const float* bm   = (const float*)d_in[5];
    const float* emb  = (const float*)d_in[6];
    const float* Wih  = (const float*)d_in[7];
    const float* Whh  = (const float*)d_in[8];
    const float* bih  = (const float*)d_in[9];
    const float* bhh  = (const float*)d_in[10];

    int N = in_sizes[0] / H;
    int E = in_sizes[2];

    // ws layout:
    unsigned short* S_b   = (unsigned short*)d_ws;               // N*H bf16
    unsigned short* h_b   = S_b + (size_t)N * H;                 // N*H bf16
    unsigned short* Wcs   = h_b + (size_t)N * H;                 // 3*H*H (swizzled)
    unsigned short* Whhs  = Wcs + 3 * H * H;                     // 3*H*H (swizzled)
    unsigned short* embWs = Whhs + 3 * H * H;                    // 3*8*64*8 = 12288
    u64* cnt    = (u64*)(embWs + 12288);                         // N (8B-aligned)
    int* head   = (int*)(cnt + N);                               // 4*N
    int* packed = head + 4 * N;                                  // E
    int* nexte  = packed + E;                                    // E

    int total8 = N * H / 8;
    int N4 = N * 4;
    int HB = (total8 + 255) / 256;
    int DB = (N4 + 255) / 256;
    int PB = 264;
    fused_pre_kernel<<<HB + DB + PB, 256, 0, stream>>>(
        h, h_b, total8, head, N4, Wih, Whh, Wm, emb, bm, Wcs, Whhs, embWs, HB, DB);

    fill_ll_kernel<<<(E + 255) / 256, 256, 0, stream>>>(
        eidx, etype, head, nexte, packed, E);

    gather_ll_kernel<<<(N + 7) / 8, 256, 0, stream>>>(
        h_b, head, nexte, packed, S_b, cnt, N);

    int nblk = ((N + 63) / 64) * 2;
    gru_mfma_kernel<<<nblk, 256, 0, stream>>>(S_b, h_b, Wcs, Whhs, embWs,
                                              bih, bhh, cnt, numn, (float*)d_out, N);
}

// Round 8
// 194.663 us; speedup vs baseline: 3.4897x; 1.1290x over previous
//
#include <hip/hip_runtime.h>
#include <math.h>

#define H 128
typedef unsigned int u32;
typedef unsigned long long u64;
typedef __attribute__((ext_vector_type(8))) short short8;
typedef __attribute__((ext_vector_type(4))) float floatx4;

#define XS_STRIDE 136   // bf16 elems per padded row (128 + 8) -> 272B
#define CS_STRIDE 40    // counts row stride (80B) -> conflict-free b128 reads
#define CAP 64          // bucket capacity per node (Poisson(12), max ~40)

__device__ __forceinline__ float sigmoid_f(float x) {
    return 1.0f / (1.0f + __expf(-x));
}
__device__ __forceinline__ float tanh_f(float x) {
    float t = __expf(-2.0f * fabsf(x));
    float r = (1.0f - t) / (1.0f + t);
    return copysignf(r, x);
}
// f32 -> bf16 bits, round-to-nearest-even (finite inputs)
__device__ __forceinline__ unsigned short f2bf(float x) {
    u32 u = __float_as_uint(x);
    return (unsigned short)((u + 0x7fffu + ((u >> 16) & 1u)) >> 16);
}
__device__ __forceinline__ float bf2f(unsigned short s) {
    return __uint_as_float(((u32)s) << 16);
}
__device__ __forceinline__ float bf_lo32(u32 u) { return __uint_as_float(u << 16); }
__device__ __forceinline__ float bf_hi32(u32 u) { return __uint_as_float(u & 0xffff0000u); }

// ---------------------------------------------------------------------------
// Fused pre-pass: [blocks 0..HB)   h (f32) -> h_b (bf16)
//                 [HB..HB+DB)      deg[]=0, ohead[]=-1
//                 [HB+DB..)        weight prep (W_c fold, embW', Whh swizzle)
// Swizzle (B-frag, 16x16x32): frag[((gtile*4+kc)*64 + l)*8 + i] =
//   W[(gtile*16 + (l&15))][kc*32 + (l>>4)*8 + i]
// ---------------------------------------------------------------------------
__global__ __launch_bounds__(256) void fused_pre_kernel(
    const float* __restrict__ h, unsigned short* __restrict__ h_b, int total8,
    int* __restrict__ deg, int* __restrict__ ohead, int N,
    const float* __restrict__ Wih, const float* __restrict__ Whh,
    const float* __restrict__ Wm,  const float* __restrict__ emb,
    const float* __restrict__ bm,
    unsigned short* __restrict__ Wcs, unsigned short* __restrict__ Whhs,
    unsigned short* __restrict__ embWs, int HB, int DB)
{
    int b = blockIdx.x;
    if (b < HB) {
        int idx = b * 256 + threadIdx.x;
        if (idx >= total8) return;
        const float4* p = (const float4*)(h + (size_t)idx * 8);
        float4 a = p[0], bb = p[1];
        short8 v;
        v[0] = (short)f2bf(a.x);  v[1] = (short)f2bf(a.y);
        v[2] = (short)f2bf(a.z);  v[3] = (short)f2bf(a.w);
        v[4] = (short)f2bf(bb.x); v[5] = (short)f2bf(bb.y);
        v[6] = (short)f2bf(bb.z); v[7] = (short)f2bf(bb.w);
        *(short8*)(h_b + (size_t)idx * 8) = v;
        return;
    }
    if (b < HB + DB) {
        int idx = (b - HB) * 256 + threadIdx.x;
        if (idx < N) deg[idx] = 0;
        else if (idx < 2 * N) ohead[idx - N] = -1;
        return;
    }
    int idx = (b - HB - DB) * 256 + threadIdx.x;
    if (idx < 49152) {
        // ---- W_c[g][k] = sum_c Wih[g][c] * Wm[c][k], f32 acc -> bf16 swizzled
        int g = idx >> 7;          // 0..383
        int k = idx & 127;
        float acc = 0.f;
#pragma unroll 4
        for (int c = 0; c < H; ++c)
            acc += Wih[(size_t)g * H + c] * Wm[(size_t)c * H + k];
        int gate = g >> 7;
        int wi = g & 127;
        int j = wi >> 4, m = wi & 15;
        int kc = k >> 5, q = (k >> 3) & 3, i = k & 7;
        int l = q * 16 + m;
        Wcs[(size_t)(((gate * 8 + j) * 4 + kc) * 64 + l) * 8 + i] = f2bf(acc);
    } else if (idx < 61440) {
        // ---- embW'[t][g] = sum_j (emb[t][j]+bm[j])*Wih[g][j], K=32 frag
        int s = idx - 49152;       // 0..12287
        int i = s & 7;
        int l = (s >> 3) & 63;
        int jb = s >> 9;           // gate*8 + j
        int gate = jb >> 3, jj = jb & 7;
        int q = l >> 4, m = l & 15;
        int t = q * 8 + i;         // edge type (K index)
        unsigned short v = 0;
        if (t < 9) {
            int g = gate * 128 + jj * 16 + m;
            float acc = 0.f;
#pragma unroll 4
            for (int jx = 0; jx < H; ++jx)
                acc += (emb[(size_t)t * H + jx] + bm[jx]) * Wih[(size_t)g * H + jx];
            v = f2bf(acc);
        }
        embWs[s] = v;
    } else if (idx < 67584) {
        // ---- Whh convert + swizzle
        int t2 = idx - 61440;      // 0..6143
        int l  = t2 & 63;
        int kc = (t2 >> 6) & 3;
        int jr = t2 >> 8;
        int m = l & 15, q = l >> 4;
        size_t srco = (size_t)(jr * 16 + m) * H + kc * 32 + q * 8;
        const float4* s0 = (const float4*)(Whh + srco);
        float4 a = s0[0], bb = s0[1];
        short8 v;
        v[0] = (short)f2bf(a.x);  v[1] = (short)f2bf(a.y);
        v[2] = (short)f2bf(a.z);  v[3] = (short)f2bf(a.w);
        v[4] = (short)f2bf(bb.x); v[5] = (short)f2bf(bb.y);
        v[6] = (short)f2bf(bb.z); v[7] = (short)f2bf(bb.w);
        *(short8*)(Whhs + (size_t)t2 * 8) = v;
    }
}

// ---------------------------------------------------------------------------
// Bucket fill (1 dispatch, replaces CSR build): slot = atomicAdd(deg[dst]).
// Overflow (deg > CAP, essentially never for Poisson(12)) goes to a
// per-node linked list for guaranteed correctness.
// ---------------------------------------------------------------------------
__global__ __launch_bounds__(256) void fill_bucket_kernel(
    const int* __restrict__ eidx, const int* __restrict__ etype,
    int* __restrict__ deg, int* __restrict__ slots,
    int* __restrict__ ohead, int* __restrict__ onext,
    int* __restrict__ packed, int E)
{
    int e = blockIdx.x * 256 + threadIdx.x;
    if (e >= E) return;
    int src = eidx[e];
    int dst = eidx[E + e];
    int t = etype[e];
    t = t < 0 ? 0 : (t > 8 ? 8 : t);
    int enc = src | (t << 24);
    int p = atomicAdd(&deg[dst], 1);
    if (p < CAP) {
        slots[(size_t)dst * CAP + p] = enc;
    } else {
        packed[e] = enc;
        int old = atomicExch(&ohead[dst], e);
        onext[e] = old;
    }
}

// ---------------------------------------------------------------------------
// Gather over bucket slots: S[n] = sum h_b[src], cnt[n] packed type counts.
// One wave per node; slot reads contiguous + independent (no chains),
// 8-wide unrolled for deep MLP. Rare overflow chain handled at the end.
// ---------------------------------------------------------------------------
__global__ __launch_bounds__(256) void gather_bucket_kernel(
    const unsigned short* __restrict__ h_b,
    const int* __restrict__ deg, const int* __restrict__ slots,
    const int* __restrict__ ohead, const int* __restrict__ onext,
    const int* __restrict__ packed,
    unsigned short* __restrict__ S_b, u64* __restrict__ cnt, int N)
{
    int n = blockIdx.x * 4 + (threadIdx.x >> 6);
    if (n >= N) return;
    int lane = threadIdx.x & 63;
    int dcnt = deg[n];
    int m = dcnt < CAP ? dcnt : CAP;
    const int* row = slots + (size_t)n * CAP;

    float ax = 0.f, ay = 0.f;
    u64 c = 0;
    int i = 0;
    for (; i + 8 <= m; i += 8) {
        int u0 = row[i + 0];
        int u1 = row[i + 1];
        int u2 = row[i + 2];
        int u3 = row[i + 3];
        int u4 = row[i + 4];
        int u5 = row[i + 5];
        int u6 = row[i + 6];
        int u7 = row[i + 7];
        u32 x0 = *((const u32*)(h_b + (size_t)(u0 & 0xffffff) * H) + lane);
        u32 x1 = *((const u32*)(h_b + (size_t)(u1 & 0xffffff) * H) + lane);
        u32 x2 = *((const u32*)(h_b + (size_t)(u2 & 0xffffff) * H) + lane);
        u32 x3 = *((const u32*)(h_b + (size_t)(u3 & 0xffffff) * H) + lane);
        u32 x4 = *((const u32*)(h_b + (size_t)(u4 & 0xffffff) * H) + lane);
        u32 x5 = *((const u32*)(h_b + (size_t)(u5 & 0xffffff) * H) + lane);
        u32 x6 = *((const u32*)(h_b + (size_t)(u6 & 0xffffff) * H) + lane);
        u32 x7 = *((const u32*)(h_b + (size_t)(u7 & 0xffffff) * H) + lane);
        c += (1ull << (7 * (u0 >> 24))) + (1ull << (7 * (u1 >> 24)))
           + (1ull << (7 * (u2 >> 24))) + (1ull << (7 * (u3 >> 24)))
           + (1ull << (7 * (u4 >> 24))) + (1ull << (7 * (u5 >> 24)))
           + (1ull << (7 * (u6 >> 24))) + (1ull << (7 * (u7 >> 24)));
        ax += bf_lo32(x0) + bf_lo32(x1) + bf_lo32(x2) + bf_lo32(x3)
            + bf_lo32(x4) + bf_lo32(x5) + bf_lo32(x6) + bf_lo32(x7);
        ay += bf_hi32(x0) + bf_hi32(x1) + bf_hi32(x2) + bf_hi32(x3)
            + bf_hi32(x4) + bf_hi32(x5) + bf_hi32(x6) + bf_hi32(x7);
    }
    for (; i + 4 <= m; i += 4) {
        int u0 = row[i + 0];
        int u1 = row[i + 1];
        int u2 = row[i + 2];
        int u3 = row[i + 3];
        u32 x0 = *((const u32*)(h_b + (size_t)(u0 & 0xffffff) * H) + lane);
        u32 x1 = *((const u32*)(h_b + (size_t)(u1 & 0xffffff) * H) + lane);
        u32 x2 = *((const u32*)(h_b + (size_t)(u2 & 0xffffff) * H) + lane);
        u32 x3 = *((const u32*)(h_b + (size_t)(u3 & 0xffffff) * H) + lane);
        c += (1ull << (7 * (u0 >> 24))) + (1ull << (7 * (u1 >> 24)))
           + (1ull << (7 * (u2 >> 24))) + (1ull << (7 * (u3 >> 24)));
        ax += bf_lo32(x0) + bf_lo32(x1) + bf_lo32(x2) + bf_lo32(x3);
        ay += bf_hi32(x0) + bf_hi32(x1) + bf_hi32(x2) + bf_hi32(x3);
    }
    for (; i < m; ++i) {
        int u = row[i];
        u32 x = *((const u32*)(h_b + (size_t)(u & 0xffffff) * H) + lane);
        c += 1ull << (7 * (u >> 24));
        ax += bf_lo32(x);
        ay += bf_hi32(x);
    }
    if (dcnt > CAP) {
        // overflow chain (essentially never taken; wave-uniform branch)
        int ecur = ohead[n];
        while (ecur >= 0) {
            int u = packed[ecur];
            u32 x = *((const u32*)(h_b + (size_t)(u & 0xffffff) * H) + lane);
            c += 1ull << (7 * (u >> 24));
            ax += bf_lo32(x);
            ay += bf_hi32(x);
            ecur = onext[ecur];
        }
    }
    u32 o = (u32)f2bf(ax) | ((u32)f2bf(ay) << 16);
    *((u32*)(S_b + (size_t)n * H) + lane) = o;
    if (lane == 0) cnt[n] = c;
}

// ---------------------------------------------------------------------------
// Fused GRU (MFMA). Block = (64-node tile) x (jhalf of 4 j-tiles); 4 waves,
// each wave owns ONE j-tile and loops 4 row-tiles (accs register-resident,
// weights loaded once per kc). Grid = 2x node-tiles (~1564 blocks) for
// latency hiding; LDS 39.9KB -> 4 resident blocks/CU. (r4-proven structure.)
//   aR = counts@embW_r + S@Wc_r^T + h@Whh_r^T    (gate-shared accumulators)
//   aZ = counts@embW_z + S@Wc_z^T + h@Whh_z^T
//   aIn = counts@embW_n + S@Wc_n^T ; aHn = h@Whh_n^T
// ---------------------------------------------------------------------------
__global__ __launch_bounds__(256, 4) void gru_mfma_kernel(
    const unsigned short* __restrict__ S_b, const unsigned short* __restrict__ h_b,
    const unsigned short* __restrict__ Wcs, const unsigned short* __restrict__ Whhs,
    const unsigned short* __restrict__ embWs,
    const float* __restrict__ bih, const float* __restrict__ bhh,
    const u64* __restrict__ cnt,
    const int* __restrict__ numn, float* __restrict__ out, int N)
{
    __shared__ unsigned short xs[64 * XS_STRIDE];    // 17408 B
    __shared__ unsigned short hsb[64 * XS_STRIDE];   // 17408 B
    __shared__ unsigned short cs[64 * CS_STRIDE];    //  5120 B

    int tid = threadIdx.x;
    int bx = blockIdx.x;
    int node0 = (bx >> 1) * 64;
    int jhalf = bx & 1;

    int lane = tid & 63;
    int wv = tid >> 6;
    int j = jhalf * 4 + wv;      // this wave's j-tile (0..7)

    // prefetch emb fragments (independent of staging; completes under barrier)
    short8 er = *(const short8*)(embWs + (size_t)((0 * 8 + j) * 64 + lane) * 8);
    short8 ez = *(const short8*)(embWs + (size_t)((1 * 8 + j) * 64 + lane) * 8);
    short8 en = *(const short8*)(embWs + (size_t)((2 * 8 + j) * 64 + lane) * 8);

    for (int c = tid; c < 1024; c += 256) {
        int r = c >> 4;
        int k8 = (c & 15) << 3;
        int n = node0 + r;
        int nc = n < N ? n : N - 1;
        *(short8*)(&xs[r * XS_STRIDE + k8]) =
            *(const short8*)(S_b + (size_t)nc * H + k8);
        *(short8*)(&hsb[r * XS_STRIDE + k8]) =
            *(const short8*)(h_b + (size_t)nc * H + k8);
    }
    {
        // counts tile: row r, type-group tg covers t = tg*8 .. tg*8+7 (t<9 live)
        int r = tid >> 2, tg = tid & 3;
        int n = node0 + r;
        u64 cv = cnt[n < N ? n : N - 1];
        short8 v = {0, 0, 0, 0, 0, 0, 0, 0};
        if (tg == 0) {
#pragma unroll
            for (int i = 0; i < 8; ++i)
                v[i] = (short)f2bf((float)((u32)(cv >> (7 * i)) & 127u));
        } else if (tg == 1) {
            v[0] = (short)f2bf((float)((u32)(cv >> 56) & 127u));
        }
        *(short8*)(&cs[r * CS_STRIDE + tg * 8]) = v;
    }
    __syncthreads();

    int am = lane & 15;
    int aq = lane >> 4;

    int num_nodes = numn[0];
    floatx4 zero = {0.f, 0.f, 0.f, 0.f};

    floatx4 aR[4], aZ[4], aIn[4], aHn[4];
#pragma unroll
    for (int rt = 0; rt < 4; ++rt) {
        short8 acn = *(const short8*)(&cs[(rt * 16 + am) * CS_STRIDE + aq * 8]);
        aR[rt]  = __builtin_amdgcn_mfma_f32_16x16x32_bf16(acn, er, zero, 0, 0, 0);
        aZ[rt]  = __builtin_amdgcn_mfma_f32_16x16x32_bf16(acn, ez, zero, 0, 0, 0);
        aIn[rt] = __builtin_amdgcn_mfma_f32_16x16x32_bf16(acn, en, zero, 0, 0, 0);
        aHn[rt] = zero;
    }
#pragma unroll
    for (int kc = 0; kc < 4; ++kc) {
        size_t c_r = (size_t)(((0 * 8 + j) * 4 + kc) * 64 + lane) * 8;
        size_t c_z = (size_t)(((1 * 8 + j) * 4 + kc) * 64 + lane) * 8;
        size_t c_n = (size_t)(((2 * 8 + j) * 4 + kc) * 64 + lane) * 8;
        short8 bir = *(const short8*)(Wcs + c_r);
        short8 bhr = *(const short8*)(Whhs + c_r);
        short8 biz = *(const short8*)(Wcs + c_z);
        short8 bhz = *(const short8*)(Whhs + c_z);
        short8 bin = *(const short8*)(Wcs + c_n);
        short8 bhn = *(const short8*)(Whhs + c_n);
#pragma unroll
        for (int rt = 0; rt < 4; ++rt) {
            int arow = rt * 16 + am;
            short8 axv = *(const short8*)(&xs[arow * XS_STRIDE + kc * 32 + aq * 8]);
            short8 ahv = *(const short8*)(&hsb[arow * XS_STRIDE + kc * 32 + aq * 8]);
            aR[rt]  = __builtin_amdgcn_mfma_f32_16x16x32_bf16(axv, bir, aR[rt], 0, 0, 0);
            aR[rt]  = __builtin_amdgcn_mfma_f32_16x16x32_bf16(ahv, bhr, aR[rt], 0, 0, 0);
            aZ[rt]  = __builtin_amdgcn_mfma_f32_16x16x32_bf16(axv, biz, aZ[rt], 0, 0, 0);
            aZ[rt]  = __builtin_amdgcn_mfma_f32_16x16x32_bf16(ahv, bhz, aZ[rt], 0, 0, 0);
            aIn[rt] = __builtin_amdgcn_mfma_f32_16x16x32_bf16(axv, bin, aIn[rt], 0, 0, 0);
            aHn[rt] = __builtin_amdgcn_mfma_f32_16x16x32_bf16(ahv, bhn, aHn[rt], 0, 0, 0);
        }
    }
    int c = j * 16 + am;
    float b_r = bih[c]       + bhh[c];
    float b_z = bih[128 + c] + bhh[128 + c];
    float b_in = bih[256 + c], b_hn = bhh[256 + c];
#pragma unroll
    for (int rt = 0; rt < 4; ++rt) {
#pragma unroll
        for (int q = 0; q < 4; ++q) {
            int m = rt * 16 + aq * 4 + q;
            int node = node0 + m;
            if (node < N) {
                float r  = sigmoid_f(aR[rt][q] + b_r);
                float z  = sigmoid_f(aZ[rt][q] + b_z);
                float nv = tanh_f((aIn[rt][q] + b_in) + r * (aHn[rt][q] + b_hn));
                float hv = bf2f(hsb[m * XS_STRIDE + c]);
                float o  = (1.0f - z) * nv + z * hv;
                out[(size_t)node * H + c] = (node < num_nodes) ? o : 0.0f;
            }
        }
    }
}

extern "C" void kernel_launch(void* const* d_in, const int* in_sizes, int n_in,
                              void* d_out, int out_size, void* d_ws, size_t ws_size,
                              hipStream_t stream) {
    const float* h    = (const float*)d_in[0];
    const int*  eidx  = (const int*)d_in[1];
    const int*  etype = (const int*)d_in[2];
    const int*  numn  = (const int*)d_in[3];
    const float* Wm   = (const float*)d_in[4];
    const float* bm   = (const float*)d_in[5];
    const float* emb  = (const float*)d_in[6];
    const float* Wih  = (const float*)d_in[7];
    const float* Whh  = (const float*)d_in[8];
    const float* bih  = (const float*)d_in[9];
    const float* bhh  = (const float*)d_in[10];

    int N = in_sizes[0] / H;
    int E = in_sizes[2];

    // ws layout:
    unsigned short* S_b   = (unsigned short*)d_ws;               // N*H bf16
    unsigned short* h_b   = S_b + (size_t)N * H;                 // N*H bf16
    unsigned short* Wcs   = h_b + (size_t)N * H;                 // 3*H*H (swizzled)
    unsigned short* Whhs  = Wcs + 3 * H * H;                     // 3*H*H (swizzled)
    unsigned short* embWs = Whhs + 3 * H * H;                    // 3*8*64*8 = 12288
    u64* cnt    = (u64*)(embWs + 12288);                         // N (8B-aligned)
    int* deg    = (int*)(cnt + N);                               // N
    int* ohead  = deg + N;                                       // N
    int* slots  = ohead + N;                                     // N*CAP
    int* packed = slots + (size_t)N * CAP;                       // E (overflow enc)
    int* onext  = packed + E;                                    // E

    int total8 = N * H / 8;
    int HB = (total8 + 255) / 256;
    int DB = (2 * N + 255) / 256;
    int PB = 264;
    fused_pre_kernel<<<HB + DB + PB, 256, 0, stream>>>(
        h, h_b, total8, deg, ohead, N, Wih, Whh, Wm, emb, bm, Wcs, Whhs, embWs,
        HB, DB);

    fill_bucket_kernel<<<(E + 255) / 256, 256, 0, stream>>>(
        eidx, etype, deg, slots, ohead, onext, packed, E);

    gather_bucket_kernel<<<(N + 3) / 4, 256, 0, stream>>>(
        h_b, deg, slots, ohead, onext, packed, S_b, cnt, N);

    int nblk = ((N + 63) / 64) * 2;
    gru_mfma_kernel<<<nblk, 256, 0, stream>>>(S_b, h_b, Wcs, Whhs, embWs,
                                              bih, bhh, cnt, numn, (float*)d_out, N);
}